// Round 5
// baseline (467.629 us; speedup 1.0000x reference)
//
#include <hip/hip_runtime.h>

#define NN 50000
#define NE 800000

__device__ inline float rlf(float v, int l) {
    return __int_as_float(__builtin_amdgcn_readlane(__float_as_int(v), l));
}

// ---------------- CSR build ----------------
__global__ void k_hist(const int* __restrict__ dst, int* __restrict__ cnt) {
    int e = blockIdx.x * 256 + threadIdx.x;
    if (e < NE) atomicAdd(&cnt[dst[e]], 1);
}

__global__ void k_disq(const int* __restrict__ cnt, float* __restrict__ disq) {
    int i = blockIdx.x * 256 + threadIdx.x;
    if (i < NN) disq[i] = rsqrtf((float)cnt[i] + 1.0f);  // +1 self-loop
}

// single-block inclusive scan: rowptr[i+1] = sum(cnt[0..i]), rowptr[0] = 0
__global__ __launch_bounds__(1024) void k_scan(const int* __restrict__ cnt,
                                               int* __restrict__ rowptr) {
    __shared__ int wsum[16];
    __shared__ int carry;
    int t = threadIdx.x, wave = t >> 6, lane = t & 63;
    if (t == 0) { carry = 0; rowptr[0] = 0; }
    __syncthreads();
    for (int base = 0; base < NN; base += 1024) {
        int i = base + t;
        int x = (i < NN) ? cnt[i] : 0;
        for (int off = 1; off < 64; off <<= 1) {
            int y = __shfl_up(x, off, 64);
            if (lane >= off) x += y;
        }
        if (lane == 63) wsum[wave] = x;
        __syncthreads();
        if (wave == 0 && lane < 16) {
            int w = wsum[lane];
            for (int off = 1; off < 16; off <<= 1) {
                int y = __shfl_up(w, off, 16);
                if (lane >= off) w += y;
            }
            wsum[lane] = w;
        }
        __syncthreads();
        int incl = carry + ((wave > 0) ? wsum[wave - 1] : 0) + x;
        if (i < NN) rowptr[i + 1] = incl;
        __syncthreads();
        if (t == 1023) carry = incl;
        __syncthreads();
    }
}

__global__ void k_fill(const int* __restrict__ src, const int* __restrict__ dst,
                       const int* __restrict__ rowptr, int* __restrict__ cur,
                       int* __restrict__ esrc) {
    int e = blockIdx.x * 256 + threadIdx.x;
    if (e < NE) {
        int d = dst[e];
        int pos = rowptr[d] + atomicAdd(&cur[d], 1);
        esrc[pos] = src[e];
    }
}

// ---------------- fc stack: X = relu(nf@W1+b1)@W2+b2 ----------------
// wave per 2 nodes: two independent FMA chains share the w-value stream
__global__ __launch_bounds__(256) void k_fc(
    const float* __restrict__ nf,
    const float* __restrict__ W1, const float* __restrict__ b1,
    const float* __restrict__ W2, const float* __restrict__ b2,
    float* __restrict__ X) {
    int lane = threadIdx.x & 63;
    int c = lane & 31, h = lane >> 5;
    int wid = (blockIdx.x * 256 + threadIdx.x) >> 6;
    int nwaves = (gridDim.x * 256) >> 6;
    float w1[64], w2[32];
    #pragma unroll
    for (int j = 0; j < 64; ++j) w1[j] = W1[(h * 64 + j) * 32 + c];
    #pragma unroll
    for (int j = 0; j < 32; ++j) w2[j] = W2[j * 64 + lane];
    float b1c = b1[c], b2l = b2[lane];
    const int npairs = NN / 2;  // 25000
    for (int p = wid; p < npairs; p += nwaves) {
        int n0 = 2 * p, n1 = n0 + 1;
        float x0a = nf[(size_t)n0 * 128 + lane];
        float x1a = nf[(size_t)n0 * 128 + 64 + lane];
        float x0b = nf[(size_t)n1 * 128 + lane];
        float x1b = nf[(size_t)n1 * 128 + 64 + lane];
        float sa = 0.f, sb = 0.f;
        #pragma unroll
        for (int j = 0; j < 64; ++j) {
            float wj = w1[j];
            float va = h ? rlf(x1a, j) : rlf(x0a, j);
            float vb = h ? rlf(x1b, j) : rlf(x0b, j);
            sa = fmaf(va, wj, sa);
            sb = fmaf(vb, wj, sb);
        }
        sa += __shfl_xor(sa, 32, 64);          // combine k-halves
        sb += __shfl_xor(sb, 32, 64);
        float hva = fmaxf(sa + b1c, 0.f);      // lane l holds h1[l&31]
        float hvb = fmaxf(sb + b1c, 0.f);
        float oa = b2l, ob = b2l;
        #pragma unroll
        for (int j = 0; j < 32; ++j) {
            float wj = w2[j];
            oa = fmaf(rlf(hva, j), wj, oa);
            ob = fmaf(rlf(hvb, j), wj, ob);
        }
        X[(size_t)n0 * 64 + lane] = oa;
        X[(size_t)n1 * 64 + lane] = ob;
    }
}

// ---------------- conv GEMM: H[n] = disq[n] * (X[n] @ W) ----------------
// wave per node, lane = output channel, W column in 64 VGPRs, no LDS
__global__ __launch_bounds__(256) void k_gemm64(
    const float* __restrict__ X, const float* __restrict__ W,
    const float* __restrict__ disq, float* __restrict__ Hout) {
    int lane = threadIdx.x & 63;
    int wid = (blockIdx.x * 256 + threadIdx.x) >> 6;
    int nwaves = (gridDim.x * 256) >> 6;
    float wcol[64];
    #pragma unroll
    for (int k = 0; k < 64; ++k) wcol[k] = W[k * 64 + lane];
    for (int n = wid; n < NN; n += nwaves) {
        float xv = X[(size_t)n * 64 + lane];
        float acc = 0.f;
        #pragma unroll
        for (int k = 0; k < 64; ++k) acc = fmaf(rlf(xv, k), wcol[k], acc);
        Hout[(size_t)n * 64 + lane] = disq[n] * acc;
    }
}

// ---------------- CSR conv: out = act(disq*(sum_neigh H + H_self) + b) [+res]
// one wave per node, lane = channel; cooperative index fetch, 8-deep gathers
__global__ __launch_bounds__(256) void k_csr_conv(
    const float* __restrict__ H, const int* __restrict__ rowptr,
    const int* __restrict__ esrc, const float* __restrict__ disq,
    const float* __restrict__ b, const float* __restrict__ res,
    float* __restrict__ out, int do_lrelu) {
    int lane = threadIdx.x & 63;
    int n = (blockIdx.x * 256 + threadIdx.x) >> 6;
    if (n >= NN) return;
    int beg = rowptr[n], end = rowptr[n + 1];
    float acc = H[(size_t)n * 64 + lane];  // self-loop
    for (int base = beg; base < end; base += 64) {
        int cnt = min(64, end - base);
        int idx = (lane < cnt) ? esrc[base + lane] : 0;
        int j = 0;
        for (; j + 8 <= cnt; j += 8) {
            int s0 = __builtin_amdgcn_readlane(idx, j);
            int s1 = __builtin_amdgcn_readlane(idx, j + 1);
            int s2 = __builtin_amdgcn_readlane(idx, j + 2);
            int s3 = __builtin_amdgcn_readlane(idx, j + 3);
            int s4 = __builtin_amdgcn_readlane(idx, j + 4);
            int s5 = __builtin_amdgcn_readlane(idx, j + 5);
            int s6 = __builtin_amdgcn_readlane(idx, j + 6);
            int s7 = __builtin_amdgcn_readlane(idx, j + 7);
            float h0 = H[(size_t)s0 * 64 + lane];
            float h1 = H[(size_t)s1 * 64 + lane];
            float h2 = H[(size_t)s2 * 64 + lane];
            float h3 = H[(size_t)s3 * 64 + lane];
            float h4 = H[(size_t)s4 * 64 + lane];
            float h5 = H[(size_t)s5 * 64 + lane];
            float h6 = H[(size_t)s6 * 64 + lane];
            float h7 = H[(size_t)s7 * 64 + lane];
            acc += ((h0 + h1) + (h2 + h3)) + ((h4 + h5) + (h6 + h7));
        }
        for (; j + 4 <= cnt; j += 4) {
            int s0 = __builtin_amdgcn_readlane(idx, j);
            int s1 = __builtin_amdgcn_readlane(idx, j + 1);
            int s2 = __builtin_amdgcn_readlane(idx, j + 2);
            int s3 = __builtin_amdgcn_readlane(idx, j + 3);
            float h0 = H[(size_t)s0 * 64 + lane];
            float h1 = H[(size_t)s1 * 64 + lane];
            float h2 = H[(size_t)s2 * 64 + lane];
            float h3 = H[(size_t)s3 * 64 + lane];
            acc += (h0 + h1) + (h2 + h3);
        }
        for (; j < cnt; ++j) {
            int s = __builtin_amdgcn_readlane(idx, j);
            acc += H[(size_t)s * 64 + lane];
        }
    }
    float v = disq[n] * acc + b[lane];
    if (do_lrelu) v = (v >= 0.0f) ? v : 0.2f * v;
    if (res) v += res[(size_t)n * 64 + lane];
    out[(size_t)n * 64 + lane] = v;
}

// ---------------- CSR conv fused with final 64->2 projection (conv4) ----
__global__ __launch_bounds__(256) void k_csr_conv_final(
    const float* __restrict__ H, const int* __restrict__ rowptr,
    const int* __restrict__ esrc, const float* __restrict__ disq,
    const float* __restrict__ b, const float* __restrict__ res,
    const float* __restrict__ FW, const float* __restrict__ fb,
    float* __restrict__ out) {
    int lane = threadIdx.x & 63;
    int n = (blockIdx.x * 256 + threadIdx.x) >> 6;
    if (n >= NN) return;
    int beg = rowptr[n], end = rowptr[n + 1];
    float acc = H[(size_t)n * 64 + lane];
    for (int base = beg; base < end; base += 64) {
        int cnt = min(64, end - base);
        int idx = (lane < cnt) ? esrc[base + lane] : 0;
        int j = 0;
        for (; j + 8 <= cnt; j += 8) {
            int s0 = __builtin_amdgcn_readlane(idx, j);
            int s1 = __builtin_amdgcn_readlane(idx, j + 1);
            int s2 = __builtin_amdgcn_readlane(idx, j + 2);
            int s3 = __builtin_amdgcn_readlane(idx, j + 3);
            int s4 = __builtin_amdgcn_readlane(idx, j + 4);
            int s5 = __builtin_amdgcn_readlane(idx, j + 5);
            int s6 = __builtin_amdgcn_readlane(idx, j + 6);
            int s7 = __builtin_amdgcn_readlane(idx, j + 7);
            float h0 = H[(size_t)s0 * 64 + lane];
            float h1 = H[(size_t)s1 * 64 + lane];
            float h2 = H[(size_t)s2 * 64 + lane];
            float h3 = H[(size_t)s3 * 64 + lane];
            float h4 = H[(size_t)s4 * 64 + lane];
            float h5 = H[(size_t)s5 * 64 + lane];
            float h6 = H[(size_t)s6 * 64 + lane];
            float h7 = H[(size_t)s7 * 64 + lane];
            acc += ((h0 + h1) + (h2 + h3)) + ((h4 + h5) + (h6 + h7));
        }
        for (; j + 4 <= cnt; j += 4) {
            int s0 = __builtin_amdgcn_readlane(idx, j);
            int s1 = __builtin_amdgcn_readlane(idx, j + 1);
            int s2 = __builtin_amdgcn_readlane(idx, j + 2);
            int s3 = __builtin_amdgcn_readlane(idx, j + 3);
            float h0 = H[(size_t)s0 * 64 + lane];
            float h1 = H[(size_t)s1 * 64 + lane];
            float h2 = H[(size_t)s2 * 64 + lane];
            float h3 = H[(size_t)s3 * 64 + lane];
            acc += (h0 + h1) + (h2 + h3);
        }
        for (; j < cnt; ++j) {
            int s = __builtin_amdgcn_readlane(idx, j);
            acc += H[(size_t)s * 64 + lane];
        }
    }
    float v = disq[n] * acc + b[lane] + res[(size_t)n * 64 + lane];  // out4
    float p0 = v * FW[lane * 2 + 0];
    float p1 = v * FW[lane * 2 + 1];
    for (int off = 32; off; off >>= 1) {
        p0 += __shfl_xor(p0, off, 64);
        p1 += __shfl_xor(p1, off, 64);
    }
    if (lane == 0) {
        out[n * 2 + 0] = p0 + fb[0];
        out[n * 2 + 1] = p1 + fb[1];
    }
}

extern "C" void kernel_launch(void* const* d_in, const int* in_sizes, int n_in,
                              void* d_out, int out_size, void* d_ws, size_t ws_size,
                              hipStream_t stream) {
    const float* nf   = (const float*)d_in[0];
    const int*   ei   = (const int*)d_in[1];
    const float* fc1W = (const float*)d_in[2];
    const float* fc1b = (const float*)d_in[3];
    const float* fc2W = (const float*)d_in[4];
    const float* fc2b = (const float*)d_in[5];
    const float* cW[4] = {(const float*)d_in[6], (const float*)d_in[8],
                          (const float*)d_in[10], (const float*)d_in[12]};
    const float* cb[4] = {(const float*)d_in[7], (const float*)d_in[9],
                          (const float*)d_in[11], (const float*)d_in[13]};
    const float* fW = (const float*)d_in[14];
    const float* fb = (const float*)d_in[15];
    const int* src = ei;
    const int* dst = ei + NE;

    float* ws     = (float*)d_ws;
    float* disq   = ws;                          // 50048 f
    int*   cnt    = (int*)(ws + 50048);          // 50048 i (histogram, then cursor)
    int*   rowptr = cnt + 50048;                 // 50056 i
    int*   esrc   = rowptr + 50056;              // 800000 i
    float* B0     = (float*)(esrc + 800000);     // NN*64 f
    float* B1     = B0 + (size_t)NN * 64;        // NN*64 f
    float* Hh     = B1 + (size_t)NN * 64;        // NN*64 f

    // ---- CSR build (once, shared by all 4 convs) ----
    hipMemsetAsync(cnt, 0, 50048 * sizeof(int), stream);
    k_hist<<<(NE + 255) / 256, 256, 0, stream>>>(dst, cnt);
    k_disq<<<(NN + 255) / 256, 256, 0, stream>>>(cnt, disq);
    k_scan<<<1, 1024, 0, stream>>>(cnt, rowptr);
    hipMemsetAsync(cnt, 0, 50048 * sizeof(int), stream);
    k_fill<<<(NE + 255) / 256, 256, 0, stream>>>(src, dst, rowptr, cnt, esrc);

    // ---- fc stack -> B0 ----
    k_fc<<<1024, 256, 0, stream>>>(nf, fc1W, fc1b, fc2W, fc2b, B0);

    const int cgrid = (NN * 64 + 255) / 256;  // one wave per node

    // conv1: out1 -> B1
    k_gemm64<<<512, 256, 0, stream>>>(B0, cW[0], disq, Hh);
    k_csr_conv<<<cgrid, 256, 0, stream>>>(Hh, rowptr, esrc, disq, cb[0], nullptr, B1, 1);
    // conv2: out2 = lrelu(conv)+out1 -> B0
    k_gemm64<<<512, 256, 0, stream>>>(B1, cW[1], disq, Hh);
    k_csr_conv<<<cgrid, 256, 0, stream>>>(Hh, rowptr, esrc, disq, cb[1], B1, B0, 1);
    // conv3: out3 -> B1
    k_gemm64<<<512, 256, 0, stream>>>(B0, cW[2], disq, Hh);
    k_csr_conv<<<cgrid, 256, 0, stream>>>(Hh, rowptr, esrc, disq, cb[2], nullptr, B1, 1);
    // conv4 + final projection -> d_out
    k_gemm64<<<512, 256, 0, stream>>>(B1, cW[3], disq, Hh);
    k_csr_conv_final<<<cgrid, 256, 0, stream>>>(Hh, rowptr, esrc, disq, cb[3], B0,
                                                fW, fb, (float*)d_out);
}

// Round 7
// 373.928 us; speedup vs baseline: 1.2506x; 1.2506x over previous
//
#include <hip/hip_runtime.h>

#define NN 50000
#define NE 800000

typedef unsigned short u16;
typedef unsigned int u32;

__device__ inline float rlf(float v, int l) {
    return __int_as_float(__builtin_amdgcn_readlane(__float_as_int(v), l));
}
__device__ inline float bfu(u16 u) {
    return __uint_as_float(((u32)u) << 16);
}
__device__ inline u16 f2bf(float f) {  // round-to-nearest-even
    u32 u = __float_as_uint(f);
    u32 r = (u + 0x7FFFu + ((u >> 16) & 1u)) >> 16;
    return (u16)r;
}

// ---------------- CSR build ----------------
__global__ void k_hist(const int* __restrict__ dst, int* __restrict__ cnt) {
    int e = blockIdx.x * 256 + threadIdx.x;
    if (e < NE) atomicAdd(&cnt[dst[e]], 1);
}

__global__ void k_disq(const int* __restrict__ cnt, float* __restrict__ disq) {
    int i = blockIdx.x * 256 + threadIdx.x;
    if (i < NN) disq[i] = rsqrtf((float)cnt[i] + 1.0f);  // +1 self-loop
}

// single-block inclusive scan: rowptr[i+1] = sum(cnt[0..i]), rowptr[0] = 0
__global__ __launch_bounds__(1024) void k_scan(const int* __restrict__ cnt,
                                               int* __restrict__ rowptr) {
    __shared__ int wsum[16];
    __shared__ int carry;
    int t = threadIdx.x, wave = t >> 6, lane = t & 63;
    if (t == 0) { carry = 0; rowptr[0] = 0; }
    __syncthreads();
    for (int base = 0; base < NN; base += 1024) {
        int i = base + t;
        int x = (i < NN) ? cnt[i] : 0;
        for (int off = 1; off < 64; off <<= 1) {
            int y = __shfl_up(x, off, 64);
            if (lane >= off) x += y;
        }
        if (lane == 63) wsum[wave] = x;
        __syncthreads();
        if (wave == 0 && lane < 16) {
            int w = wsum[lane];
            for (int off = 1; off < 16; off <<= 1) {
                int y = __shfl_up(w, off, 16);
                if (lane >= off) w += y;
            }
            wsum[lane] = w;
        }
        __syncthreads();
        int incl = carry + ((wave > 0) ? wsum[wave - 1] : 0) + x;
        if (i < NN) rowptr[i + 1] = incl;
        __syncthreads();
        if (t == 1023) carry = incl;
        __syncthreads();
    }
}

__global__ void k_fill(const int* __restrict__ src, const int* __restrict__ dst,
                       const int* __restrict__ rowptr, int* __restrict__ cur,
                       int* __restrict__ esrc) {
    int e = blockIdx.x * 256 + threadIdx.x;
    if (e < NE) {
        int d = dst[e];
        int pos = rowptr[d] + atomicAdd(&cur[d], 1);
        esrc[pos] = src[e];
    }
}

// ---------------- fc stack: X = relu(nf@W1+b1)@W2+b2 (R3-proven version) ----
__global__ __launch_bounds__(256) void k_fc(
    const float* __restrict__ nf,
    const float* __restrict__ W1, const float* __restrict__ b1,
    const float* __restrict__ W2, const float* __restrict__ b2,
    float* __restrict__ X) {
    int lane = threadIdx.x & 63;
    int c = lane & 31, h = lane >> 5;
    int wid = (blockIdx.x * 256 + threadIdx.x) >> 6;
    int nwaves = (gridDim.x * 256) >> 6;
    float w1[64], w2[32];
    #pragma unroll
    for (int j = 0; j < 64; ++j) w1[j] = W1[(h * 64 + j) * 32 + c];
    #pragma unroll
    for (int j = 0; j < 32; ++j) w2[j] = W2[j * 64 + lane];
    float b1c = b1[c], b2l = b2[lane];
    for (int n = wid; n < NN; n += nwaves) {
        float x0 = nf[(size_t)n * 128 + lane];
        float x1 = nf[(size_t)n * 128 + 64 + lane];
        float s = 0.f;
        #pragma unroll
        for (int j = 0; j < 64; ++j) {
            float xa = rlf(x0, j), xb = rlf(x1, j);
            s = fmaf(h ? xb : xa, w1[j], s);
        }
        s += __shfl_xor(s, 32, 64);           // combine k-halves
        float hv = fmaxf(s + b1c, 0.f);       // lane l holds h1[l&31]
        float o = b2l;
        #pragma unroll
        for (int j = 0; j < 32; ++j) o = fmaf(rlf(hv, j), w2[j], o);
        X[(size_t)n * 64 + lane] = o;
    }
}

// ---------------- conv GEMM: Hb[n] = bf16( disq[n] * (X[n] @ W) ) ----------
// wave per node, lane = output channel, W column in 64 VGPRs, no LDS
__global__ __launch_bounds__(256) void k_gemm64(
    const float* __restrict__ X, const float* __restrict__ W,
    const float* __restrict__ disq, u16* __restrict__ Hb) {
    int lane = threadIdx.x & 63;
    int wid = (blockIdx.x * 256 + threadIdx.x) >> 6;
    int nwaves = (gridDim.x * 256) >> 6;
    float wcol[64];
    #pragma unroll
    for (int k = 0; k < 64; ++k) wcol[k] = W[k * 64 + lane];
    for (int n = wid; n < NN; n += nwaves) {
        float xv = X[(size_t)n * 64 + lane];
        float acc = 0.f;
        #pragma unroll
        for (int k = 0; k < 64; ++k) acc = fmaf(rlf(xv, k), wcol[k], acc);
        Hb[(size_t)n * 64 + lane] = f2bf(disq[n] * acc);
    }
}

// ---------------- CSR conv over bf16 H: out = act(disq*(sum H) + b) [+res] --
// one wave per node, lane = channel; cooperative index fetch, 8-deep gathers
__global__ __launch_bounds__(256) void k_csr_conv(
    const u16* __restrict__ Hb, const int* __restrict__ rowptr,
    const int* __restrict__ esrc, const float* __restrict__ disq,
    const float* __restrict__ b, const float* __restrict__ res,
    float* __restrict__ out, int do_lrelu) {
    int lane = threadIdx.x & 63;
    int n = (blockIdx.x * 256 + threadIdx.x) >> 6;
    if (n >= NN) return;
    int beg = rowptr[n], end = rowptr[n + 1];
    float acc = bfu(Hb[(size_t)n * 64 + lane]);  // self-loop
    for (int base = beg; base < end; base += 64) {
        int cnt = min(64, end - base);
        int idx = (lane < cnt) ? esrc[base + lane] : 0;
        int j = 0;
        for (; j + 8 <= cnt; j += 8) {
            int s0 = __builtin_amdgcn_readlane(idx, j);
            int s1 = __builtin_amdgcn_readlane(idx, j + 1);
            int s2 = __builtin_amdgcn_readlane(idx, j + 2);
            int s3 = __builtin_amdgcn_readlane(idx, j + 3);
            int s4 = __builtin_amdgcn_readlane(idx, j + 4);
            int s5 = __builtin_amdgcn_readlane(idx, j + 5);
            int s6 = __builtin_amdgcn_readlane(idx, j + 6);
            int s7 = __builtin_amdgcn_readlane(idx, j + 7);
            u16 h0 = Hb[(size_t)s0 * 64 + lane];
            u16 h1 = Hb[(size_t)s1 * 64 + lane];
            u16 h2 = Hb[(size_t)s2 * 64 + lane];
            u16 h3 = Hb[(size_t)s3 * 64 + lane];
            u16 h4 = Hb[(size_t)s4 * 64 + lane];
            u16 h5 = Hb[(size_t)s5 * 64 + lane];
            u16 h6 = Hb[(size_t)s6 * 64 + lane];
            u16 h7 = Hb[(size_t)s7 * 64 + lane];
            acc += ((bfu(h0) + bfu(h1)) + (bfu(h2) + bfu(h3))) +
                   ((bfu(h4) + bfu(h5)) + (bfu(h6) + bfu(h7)));
        }
        for (; j + 4 <= cnt; j += 4) {
            int s0 = __builtin_amdgcn_readlane(idx, j);
            int s1 = __builtin_amdgcn_readlane(idx, j + 1);
            int s2 = __builtin_amdgcn_readlane(idx, j + 2);
            int s3 = __builtin_amdgcn_readlane(idx, j + 3);
            u16 h0 = Hb[(size_t)s0 * 64 + lane];
            u16 h1 = Hb[(size_t)s1 * 64 + lane];
            u16 h2 = Hb[(size_t)s2 * 64 + lane];
            u16 h3 = Hb[(size_t)s3 * 64 + lane];
            acc += (bfu(h0) + bfu(h1)) + (bfu(h2) + bfu(h3));
        }
        for (; j < cnt; ++j) {
            int s = __builtin_amdgcn_readlane(idx, j);
            acc += bfu(Hb[(size_t)s * 64 + lane]);
        }
    }
    float v = disq[n] * acc + b[lane];
    if (do_lrelu) v = (v >= 0.0f) ? v : 0.2f * v;
    if (res) v += res[(size_t)n * 64 + lane];
    out[(size_t)n * 64 + lane] = v;
}

// ---------------- CSR conv fused with final 64->2 projection (conv4) ----
__global__ __launch_bounds__(256) void k_csr_conv_final(
    const u16* __restrict__ Hb, const int* __restrict__ rowptr,
    const int* __restrict__ esrc, const float* __restrict__ disq,
    const float* __restrict__ b, const float* __restrict__ res,
    const float* __restrict__ FW, const float* __restrict__ fb,
    float* __restrict__ out) {
    int lane = threadIdx.x & 63;
    int n = (blockIdx.x * 256 + threadIdx.x) >> 6;
    if (n >= NN) return;
    int beg = rowptr[n], end = rowptr[n + 1];
    float acc = bfu(Hb[(size_t)n * 64 + lane]);
    for (int base = beg; base < end; base += 64) {
        int cnt = min(64, end - base);
        int idx = (lane < cnt) ? esrc[base + lane] : 0;
        int j = 0;
        for (; j + 8 <= cnt; j += 8) {
            int s0 = __builtin_amdgcn_readlane(idx, j);
            int s1 = __builtin_amdgcn_readlane(idx, j + 1);
            int s2 = __builtin_amdgcn_readlane(idx, j + 2);
            int s3 = __builtin_amdgcn_readlane(idx, j + 3);
            int s4 = __builtin_amdgcn_readlane(idx, j + 4);
            int s5 = __builtin_amdgcn_readlane(idx, j + 5);
            int s6 = __builtin_amdgcn_readlane(idx, j + 6);
            int s7 = __builtin_amdgcn_readlane(idx, j + 7);
            u16 h0 = Hb[(size_t)s0 * 64 + lane];
            u16 h1 = Hb[(size_t)s1 * 64 + lane];
            u16 h2 = Hb[(size_t)s2 * 64 + lane];
            u16 h3 = Hb[(size_t)s3 * 64 + lane];
            u16 h4 = Hb[(size_t)s4 * 64 + lane];
            u16 h5 = Hb[(size_t)s5 * 64 + lane];
            u16 h6 = Hb[(size_t)s6 * 64 + lane];
            u16 h7 = Hb[(size_t)s7 * 64 + lane];
            acc += ((bfu(h0) + bfu(h1)) + (bfu(h2) + bfu(h3))) +
                   ((bfu(h4) + bfu(h5)) + (bfu(h6) + bfu(h7)));
        }
        for (; j + 4 <= cnt; j += 4) {
            int s0 = __builtin_amdgcn_readlane(idx, j);
            int s1 = __builtin_amdgcn_readlane(idx, j + 1);
            int s2 = __builtin_amdgcn_readlane(idx, j + 2);
            int s3 = __builtin_amdgcn_readlane(idx, j + 3);
            u16 h0 = Hb[(size_t)s0 * 64 + lane];
            u16 h1 = Hb[(size_t)s1 * 64 + lane];
            u16 h2 = Hb[(size_t)s2 * 64 + lane];
            u16 h3 = Hb[(size_t)s3 * 64 + lane];
            acc += (bfu(h0) + bfu(h1)) + (bfu(h2) + bfu(h3));
        }
        for (; j < cnt; ++j) {
            int s = __builtin_amdgcn_readlane(idx, j);
            acc += bfu(Hb[(size_t)s * 64 + lane]);
        }
    }
    float v = disq[n] * acc + b[lane] + res[(size_t)n * 64 + lane];  // out4
    float p0 = v * FW[lane * 2 + 0];
    float p1 = v * FW[lane * 2 + 1];
    for (int off = 32; off; off >>= 1) {
        p0 += __shfl_xor(p0, off, 64);
        p1 += __shfl_xor(p1, off, 64);
    }
    if (lane == 0) {
        out[n * 2 + 0] = p0 + fb[0];
        out[n * 2 + 1] = p1 + fb[1];
    }
}

extern "C" void kernel_launch(void* const* d_in, const int* in_sizes, int n_in,
                              void* d_out, int out_size, void* d_ws, size_t ws_size,
                              hipStream_t stream) {
    const float* nf   = (const float*)d_in[0];
    const int*   ei   = (const int*)d_in[1];
    const float* fc1W = (const float*)d_in[2];
    const float* fc1b = (const float*)d_in[3];
    const float* fc2W = (const float*)d_in[4];
    const float* fc2b = (const float*)d_in[5];
    const float* cW[4] = {(const float*)d_in[6], (const float*)d_in[8],
                          (const float*)d_in[10], (const float*)d_in[12]};
    const float* cb[4] = {(const float*)d_in[7], (const float*)d_in[9],
                          (const float*)d_in[11], (const float*)d_in[13]};
    const float* fW = (const float*)d_in[14];
    const float* fb = (const float*)d_in[15];
    const int* src = ei;
    const int* dst = ei + NE;

    float* ws     = (float*)d_ws;
    float* disq   = ws;                          // 50048 f
    int*   cnt    = (int*)(ws + 50048);          // 50048 i (histogram, then cursor)
    int*   rowptr = cnt + 50048;                 // 50056 i
    int*   esrc   = rowptr + 50056;              // 800000 i
    float* B0     = (float*)(esrc + 800000);     // NN*64 f
    float* B1     = B0 + (size_t)NN * 64;        // NN*64 f
    u16*   Hb     = (u16*)(B1 + (size_t)NN * 64);// NN*64 u16

    // ---- CSR build (once, shared by all 4 convs) ----
    hipMemsetAsync(cnt, 0, 50048 * sizeof(int), stream);
    k_hist<<<(NE + 255) / 256, 256, 0, stream>>>(dst, cnt);
    k_disq<<<(NN + 255) / 256, 256, 0, stream>>>(cnt, disq);
    k_scan<<<1, 1024, 0, stream>>>(cnt, rowptr);
    hipMemsetAsync(cnt, 0, 50048 * sizeof(int), stream);
    k_fill<<<(NE + 255) / 256, 256, 0, stream>>>(src, dst, rowptr, cnt, esrc);

    // ---- fc stack -> B0 ----
    k_fc<<<1024, 256, 0, stream>>>(nf, fc1W, fc1b, fc2W, fc2b, B0);

    const int cgrid = (NN * 64 + 255) / 256;  // one wave per node

    // conv1: out1 -> B1
    k_gemm64<<<512, 256, 0, stream>>>(B0, cW[0], disq, Hb);
    k_csr_conv<<<cgrid, 256, 0, stream>>>(Hb, rowptr, esrc, disq, cb[0], nullptr, B1, 1);
    // conv2: out2 = lrelu(conv)+out1 -> B0
    k_gemm64<<<512, 256, 0, stream>>>(B1, cW[1], disq, Hb);
    k_csr_conv<<<cgrid, 256, 0, stream>>>(Hb, rowptr, esrc, disq, cb[1], B1, B0, 1);
    // conv3: out3 -> B1
    k_gemm64<<<512, 256, 0, stream>>>(B0, cW[2], disq, Hb);
    k_csr_conv<<<cgrid, 256, 0, stream>>>(Hb, rowptr, esrc, disq, cb[2], nullptr, B1, 1);
    // conv4 + final projection -> d_out
    k_gemm64<<<512, 256, 0, stream>>>(B1, cW[3], disq, Hb);
    k_csr_conv_final<<<cgrid, 256, 0, stream>>>(Hb, rowptr, esrc, disq, cb[3], B0,
                                                fW, fb, (float*)d_out);
}

// Round 8
// 356.605 us; speedup vs baseline: 1.3113x; 1.0486x over previous
//
#include <hip/hip_runtime.h>

#define NN 50000
#define NE 800000

typedef unsigned short u16;
typedef unsigned int u32;

__device__ inline float rlf(float v, int l) {
    return __int_as_float(__builtin_amdgcn_readlane(__float_as_int(v), l));
}
__device__ inline u16 f2bf(float f) {  // round-to-nearest-even
    u32 u = __float_as_uint(f);
    u32 r = (u + 0x7FFFu + ((u >> 16) & 1u)) >> 16;
    return (u16)r;
}
__device__ inline float lo16(u32 q) { return __uint_as_float(q << 16); }
__device__ inline float hi16(u32 q) { return __uint_as_float(q & 0xffff0000u); }

// ---------------- CSR build ----------------
__global__ void k_hist(const int* __restrict__ dst, int* __restrict__ cnt) {
    int e = blockIdx.x * 256 + threadIdx.x;
    if (e < NE) atomicAdd(&cnt[dst[e]], 1);
}

__global__ void k_disq(const int* __restrict__ cnt, float* __restrict__ disq) {
    int i = blockIdx.x * 256 + threadIdx.x;
    if (i < NN) disq[i] = rsqrtf((float)cnt[i] + 1.0f);  // +1 self-loop
}

// single-block inclusive scan: rowptr[i+1] = sum(cnt[0..i]); also zeroes cnt
__global__ __launch_bounds__(1024) void k_scan(int* __restrict__ cnt,
                                               int* __restrict__ rowptr) {
    __shared__ int wsum[16];
    __shared__ int carry;
    int t = threadIdx.x, wave = t >> 6, lane = t & 63;
    if (t == 0) { carry = 0; rowptr[0] = 0; }
    __syncthreads();
    for (int base = 0; base < NN; base += 1024) {
        int i = base + t;
        int x = (i < NN) ? cnt[i] : 0;
        if (i < NN) cnt[i] = 0;  // reset for k_fill cursor
        for (int off = 1; off < 64; off <<= 1) {
            int y = __shfl_up(x, off, 64);
            if (lane >= off) x += y;
        }
        if (lane == 63) wsum[wave] = x;
        __syncthreads();
        if (wave == 0 && lane < 16) {
            int w = wsum[lane];
            for (int off = 1; off < 16; off <<= 1) {
                int y = __shfl_up(w, off, 16);
                if (lane >= off) w += y;
            }
            wsum[lane] = w;
        }
        __syncthreads();
        int incl = carry + ((wave > 0) ? wsum[wave - 1] : 0) + x;
        if (i < NN) rowptr[i + 1] = incl;
        __syncthreads();
        if (t == 1023) carry = incl;
        __syncthreads();
    }
}

__global__ void k_fill(const int* __restrict__ src, const int* __restrict__ dst,
                       const int* __restrict__ rowptr, int* __restrict__ cur,
                       int* __restrict__ esrc) {
    int e = blockIdx.x * 256 + threadIdx.x;
    if (e < NE) {
        int d = dst[e];
        int pos = rowptr[d] + atomicAdd(&cur[d], 1);
        esrc[pos] = src[e];
    }
}

// ---------------- weight fold: W2c = fc2W @ conv1W, b2c = b2 @ conv1W ------
__global__ __launch_bounds__(64) void k_foldw(
    const float* __restrict__ fc2W, const float* __restrict__ b2,
    const float* __restrict__ c1W, float* __restrict__ W2c,
    float* __restrict__ b2c) {
    int c = threadIdx.x;  // 0..63
    int j = blockIdx.x;   // 0..32 (row 32 = bias)
    float s = 0.f;
    if (j < 32) {
        for (int k = 0; k < 64; ++k) s = fmaf(fc2W[j * 64 + k], c1W[k * 64 + c], s);
        W2c[j * 64 + c] = s;
    } else {
        for (int k = 0; k < 64; ++k) s = fmaf(b2[k], c1W[k * 64 + c], s);
        b2c[c] = s;
    }
}

// ---------------- fc stack fused with conv1 GEMM ----------------
// Hb1[n] = bf16( disq[n] * (relu(nf@W1+b1) @ W2c + b2c) )
__global__ __launch_bounds__(256) void k_fc(
    const float* __restrict__ nf,
    const float* __restrict__ W1, const float* __restrict__ b1,
    const float* __restrict__ W2c, const float* __restrict__ b2c,
    const float* __restrict__ disq, u16* __restrict__ Hb) {
    int lane = threadIdx.x & 63;
    int c = lane & 31, h = lane >> 5;
    int wid = (blockIdx.x * 256 + threadIdx.x) >> 6;
    int nwaves = (gridDim.x * 256) >> 6;
    float w1[64], w2[32];
    #pragma unroll
    for (int j = 0; j < 64; ++j) w1[j] = W1[(h * 64 + j) * 32 + c];
    #pragma unroll
    for (int j = 0; j < 32; ++j) w2[j] = W2c[j * 64 + lane];
    float b1c = b1[c], b2l = b2c[lane];
    for (int n = wid; n < NN; n += nwaves) {
        float x0 = nf[(size_t)n * 128 + lane];
        float x1 = nf[(size_t)n * 128 + 64 + lane];
        float s = 0.f;
        #pragma unroll
        for (int j = 0; j < 64; ++j) {
            float xa = rlf(x0, j), xb = rlf(x1, j);
            s = fmaf(h ? xb : xa, w1[j], s);
        }
        s += __shfl_xor(s, 32, 64);           // combine k-halves
        float hv = fmaxf(s + b1c, 0.f);       // lane l holds h1[l&31]
        float o = b2l;
        #pragma unroll
        for (int j = 0; j < 32; ++j) o = fmaf(rlf(hv, j), w2[j], o);
        Hb[(size_t)n * 64 + lane] = f2bf(disq[n] * o);
    }
}

// ---------------- conv GEMM: Hb[n] = bf16( disq[n] * (X[n] @ W) ) ----------
__global__ __launch_bounds__(256) void k_gemm64(
    const float* __restrict__ X, const float* __restrict__ W,
    const float* __restrict__ disq, u16* __restrict__ Hb) {
    int lane = threadIdx.x & 63;
    int wid = (blockIdx.x * 256 + threadIdx.x) >> 6;
    int nwaves = (gridDim.x * 256) >> 6;
    float wcol[64];
    #pragma unroll
    for (int k = 0; k < 64; ++k) wcol[k] = W[k * 64 + lane];
    for (int n = wid; n < NN; n += nwaves) {
        float xv = X[(size_t)n * 64 + lane];
        float acc = 0.f;
        #pragma unroll
        for (int k = 0; k < 64; ++k) acc = fmaf(rlf(xv, k), wcol[k], acc);
        Hb[(size_t)n * 64 + lane] = f2bf(disq[n] * acc);
    }
}

// ---------------- CSR conv, paired-row u32 gathers ----------------
// wave per node; lane owns channels (cl, cl+1); half-waves cover 2 rows/load
__global__ __launch_bounds__(256) void k_csr_conv(
    const u16* __restrict__ Hb, const int* __restrict__ rowptr,
    const int* __restrict__ esrc, const float* __restrict__ disq,
    const float* __restrict__ b, const float* __restrict__ res,
    float* __restrict__ out, int do_lrelu) {
    int lane = threadIdx.x & 63;
    int half = lane >> 5;
    int cl = (lane & 31) * 2;
    int n = (blockIdx.x * 256 + threadIdx.x) >> 6;
    if (n >= NN) return;
    int beg = rowptr[n], end = rowptr[n + 1];
    float a0 = 0.f, a1 = 0.f;
    for (int base = beg; base < end; base += 64) {
        int cnt = min(64, end - base);
        int idx = (lane < cnt) ? esrc[base + lane] : 0;
        int j = 0;
        for (; j + 8 <= cnt; j += 8) {
            int p0 = __builtin_amdgcn_readlane(idx, j + 0);
            int p1 = __builtin_amdgcn_readlane(idx, j + 1);
            int p2 = __builtin_amdgcn_readlane(idx, j + 2);
            int p3 = __builtin_amdgcn_readlane(idx, j + 3);
            int p4 = __builtin_amdgcn_readlane(idx, j + 4);
            int p5 = __builtin_amdgcn_readlane(idx, j + 5);
            int p6 = __builtin_amdgcn_readlane(idx, j + 6);
            int p7 = __builtin_amdgcn_readlane(idx, j + 7);
            int sA = half ? p1 : p0;
            int sB = half ? p3 : p2;
            int sC = half ? p5 : p4;
            int sD = half ? p7 : p6;
            u32 qA = *(const u32*)(Hb + ((size_t)sA * 64 + cl));
            u32 qB = *(const u32*)(Hb + ((size_t)sB * 64 + cl));
            u32 qC = *(const u32*)(Hb + ((size_t)sC * 64 + cl));
            u32 qD = *(const u32*)(Hb + ((size_t)sD * 64 + cl));
            a0 += (lo16(qA) + lo16(qB)) + (lo16(qC) + lo16(qD));
            a1 += (hi16(qA) + hi16(qB)) + (hi16(qC) + hi16(qD));
        }
        for (; j + 2 <= cnt; j += 2) {
            int p0 = __builtin_amdgcn_readlane(idx, j);
            int p1 = __builtin_amdgcn_readlane(idx, j + 1);
            int s = half ? p1 : p0;
            u32 q = *(const u32*)(Hb + ((size_t)s * 64 + cl));
            a0 += lo16(q);
            a1 += hi16(q);
        }
        if (j < cnt) {  // odd tail: half 0 only
            int s = __builtin_amdgcn_readlane(idx, j);
            if (!half) {
                u32 q = *(const u32*)(Hb + ((size_t)s * 64 + cl));
                a0 += lo16(q);
                a1 += hi16(q);
            }
        }
    }
    a0 += __shfl_xor(a0, 32, 64);  // combine even/odd row halves
    a1 += __shfl_xor(a1, 32, 64);
    u32 qs = *(const u32*)(Hb + ((size_t)n * 64 + cl));  // self-loop
    a0 += lo16(qs);
    a1 += hi16(qs);
    float dn = disq[n];
    float v0 = dn * a0 + b[cl];
    float v1 = dn * a1 + b[cl + 1];
    if (do_lrelu) {
        v0 = (v0 >= 0.f) ? v0 : 0.2f * v0;
        v1 = (v1 >= 0.f) ? v1 : 0.2f * v1;
    }
    if (res) {
        float2 r = *(const float2*)(res + ((size_t)n * 64 + cl));
        v0 += r.x;
        v1 += r.y;
    }
    if (!half) {
        float2 o;
        o.x = v0;
        o.y = v1;
        *(float2*)(out + ((size_t)n * 64 + cl)) = o;
    }
}

// ---------------- conv4 + residual + final 64->2 projection ----------------
__global__ __launch_bounds__(256) void k_csr_conv_final(
    const u16* __restrict__ Hb, const int* __restrict__ rowptr,
    const int* __restrict__ esrc, const float* __restrict__ disq,
    const float* __restrict__ b, const float* __restrict__ res,
    const float* __restrict__ FW, const float* __restrict__ fb,
    float* __restrict__ out) {
    int lane = threadIdx.x & 63;
    int half = lane >> 5;
    int cl = (lane & 31) * 2;
    int n = (blockIdx.x * 256 + threadIdx.x) >> 6;
    if (n >= NN) return;
    int beg = rowptr[n], end = rowptr[n + 1];
    float a0 = 0.f, a1 = 0.f;
    for (int base = beg; base < end; base += 64) {
        int cnt = min(64, end - base);
        int idx = (lane < cnt) ? esrc[base + lane] : 0;
        int j = 0;
        for (; j + 8 <= cnt; j += 8) {
            int p0 = __builtin_amdgcn_readlane(idx, j + 0);
            int p1 = __builtin_amdgcn_readlane(idx, j + 1);
            int p2 = __builtin_amdgcn_readlane(idx, j + 2);
            int p3 = __builtin_amdgcn_readlane(idx, j + 3);
            int p4 = __builtin_amdgcn_readlane(idx, j + 4);
            int p5 = __builtin_amdgcn_readlane(idx, j + 5);
            int p6 = __builtin_amdgcn_readlane(idx, j + 6);
            int p7 = __builtin_amdgcn_readlane(idx, j + 7);
            int sA = half ? p1 : p0;
            int sB = half ? p3 : p2;
            int sC = half ? p5 : p4;
            int sD = half ? p7 : p6;
            u32 qA = *(const u32*)(Hb + ((size_t)sA * 64 + cl));
            u32 qB = *(const u32*)(Hb + ((size_t)sB * 64 + cl));
            u32 qC = *(const u32*)(Hb + ((size_t)sC * 64 + cl));
            u32 qD = *(const u32*)(Hb + ((size_t)sD * 64 + cl));
            a0 += (lo16(qA) + lo16(qB)) + (lo16(qC) + lo16(qD));
            a1 += (hi16(qA) + hi16(qB)) + (hi16(qC) + hi16(qD));
        }
        for (; j + 2 <= cnt; j += 2) {
            int p0 = __builtin_amdgcn_readlane(idx, j);
            int p1 = __builtin_amdgcn_readlane(idx, j + 1);
            int s = half ? p1 : p0;
            u32 q = *(const u32*)(Hb + ((size_t)s * 64 + cl));
            a0 += lo16(q);
            a1 += hi16(q);
        }
        if (j < cnt) {
            int s = __builtin_amdgcn_readlane(idx, j);
            if (!half) {
                u32 q = *(const u32*)(Hb + ((size_t)s * 64 + cl));
                a0 += lo16(q);
                a1 += hi16(q);
            }
        }
    }
    a0 += __shfl_xor(a0, 32, 64);
    a1 += __shfl_xor(a1, 32, 64);
    u32 qs = *(const u32*)(Hb + ((size_t)n * 64 + cl));
    a0 += lo16(qs);
    a1 += hi16(qs);
    float dn = disq[n];
    float2 r = *(const float2*)(res + ((size_t)n * 64 + cl));
    float v0 = dn * a0 + b[cl] + r.x;       // out4, no lrelu
    float v1 = dn * a1 + b[cl + 1] + r.y;
    // projection: channels cl, cl+1 -> 2 outputs
    float p0 = v0 * FW[cl * 2 + 0] + v1 * FW[(cl + 1) * 2 + 0];
    float p1 = v0 * FW[cl * 2 + 1] + v1 * FW[(cl + 1) * 2 + 1];
    for (int off = 16; off; off >>= 1) {  // reduce within 32-lane half
        p0 += __shfl_xor(p0, off, 64);
        p1 += __shfl_xor(p1, off, 64);
    }
    if (lane == 0) {
        out[n * 2 + 0] = p0 + fb[0];
        out[n * 2 + 1] = p1 + fb[1];
    }
}

extern "C" void kernel_launch(void* const* d_in, const int* in_sizes, int n_in,
                              void* d_out, int out_size, void* d_ws, size_t ws_size,
                              hipStream_t stream) {
    const float* nf   = (const float*)d_in[0];
    const int*   ei   = (const int*)d_in[1];
    const float* fc1W = (const float*)d_in[2];
    const float* fc1b = (const float*)d_in[3];
    const float* fc2W = (const float*)d_in[4];
    const float* fc2b = (const float*)d_in[5];
    const float* cW[4] = {(const float*)d_in[6], (const float*)d_in[8],
                          (const float*)d_in[10], (const float*)d_in[12]};
    const float* cb[4] = {(const float*)d_in[7], (const float*)d_in[9],
                          (const float*)d_in[11], (const float*)d_in[13]};
    const float* fW = (const float*)d_in[14];
    const float* fb = (const float*)d_in[15];
    const int* src = ei;
    const int* dst = ei + NE;

    float* ws     = (float*)d_ws;
    float* disq   = ws;                          // 50048 f
    int*   cnt    = (int*)(ws + 50048);          // 50048 i (histogram, then cursor)
    int*   rowptr = cnt + 50048;                 // 50056 i
    int*   esrc   = rowptr + 50056;              // 800000 i
    float* W2c    = (float*)(esrc + 800000);     // 2048 f
    float* b2c    = W2c + 2048;                  // 64 f
    float* B0     = b2c + 64;                    // NN*64 f
    float* B1     = B0 + (size_t)NN * 64;        // NN*64 f
    u16*   Hb     = (u16*)(B1 + (size_t)NN * 64);// NN*64 u16

    // ---- CSR build (once, shared by all 4 convs) ----
    hipMemsetAsync(cnt, 0, 50048 * sizeof(int), stream);
    k_hist<<<(NE + 255) / 256, 256, 0, stream>>>(dst, cnt);
    k_disq<<<(NN + 255) / 256, 256, 0, stream>>>(cnt, disq);
    k_scan<<<1, 1024, 0, stream>>>(cnt, rowptr);  // also zeroes cnt
    k_fill<<<(NE + 255) / 256, 256, 0, stream>>>(src, dst, rowptr, cnt, esrc);

    // ---- weight fold + fc stack fused with conv1 GEMM -> Hb ----
    k_foldw<<<33, 64, 0, stream>>>(fc2W, fc2b, cW[0], W2c, b2c);
    k_fc<<<1024, 256, 0, stream>>>(nf, fc1W, fc1b, W2c, b2c, disq, Hb);

    const int cgrid = (NN * 64 + 255) / 256;  // one wave per node

    // conv1: out1 -> B1
    k_csr_conv<<<cgrid, 256, 0, stream>>>(Hb, rowptr, esrc, disq, cb[0], nullptr, B1, 1);
    // conv2: out2 = lrelu(conv)+out1 -> B0
    k_gemm64<<<512, 256, 0, stream>>>(B1, cW[1], disq, Hb);
    k_csr_conv<<<cgrid, 256, 0, stream>>>(Hb, rowptr, esrc, disq, cb[1], B1, B0, 1);
    // conv3: out3 -> B1
    k_gemm64<<<512, 256, 0, stream>>>(B0, cW[2], disq, Hb);
    k_csr_conv<<<cgrid, 256, 0, stream>>>(Hb, rowptr, esrc, disq, cb[2], nullptr, B1, 1);
    // conv4 + residual(out2=B0) + final projection -> d_out
    k_gemm64<<<512, 256, 0, stream>>>(B1, cW[3], disq, Hb);
    k_csr_conv_final<<<cgrid, 256, 0, stream>>>(Hb, rowptr, esrc, disq, cb[3], B0,
                                                fW, fb, (float*)d_out);
}

// Round 9
// 353.412 us; speedup vs baseline: 1.3232x; 1.0090x over previous
//
#include <hip/hip_runtime.h>

#define NN 50000
#define NE 800000
#define HIST_BLOCKS ((NE + 255) / 256)   // 3125
#define FILL_BLOCKS HIST_BLOCKS          // 3125
#define FC_BLOCKS 1024

typedef unsigned short u16;
typedef unsigned int u32;

__device__ inline float rlf(float v, int l) {
    return __int_as_float(__builtin_amdgcn_readlane(__float_as_int(v), l));
}
__device__ inline u16 f2bf(float f) {  // round-to-nearest-even
    u32 u = __float_as_uint(f);
    u32 r = (u + 0x7FFFu + ((u >> 16) & 1u)) >> 16;
    return (u16)r;
}
__device__ inline float lo16(u32 q) { return __uint_as_float(q << 16); }
__device__ inline float hi16(u32 q) { return __uint_as_float(q & 0xffff0000u); }

// ---------------- hist (edges) + weight-fold (W2c = fc2W@c1W) dual-role ----
__global__ __launch_bounds__(256) void k_hist_foldw(
    const int* __restrict__ dst, int* __restrict__ cnt,
    const float* __restrict__ fc2W, const float* __restrict__ b2,
    const float* __restrict__ c1W, float* __restrict__ W2c,
    float* __restrict__ b2c) {
    if (blockIdx.x < HIST_BLOCKS) {
        int e = blockIdx.x * 256 + threadIdx.x;
        if (e < NE) atomicAdd(&cnt[dst[e]], 1);
    } else {
        int j = (blockIdx.x - HIST_BLOCKS) * 4 + (threadIdx.x >> 6);
        int c = threadIdx.x & 63;
        if (j < 32) {
            float s = 0.f;
            for (int k = 0; k < 64; ++k) s = fmaf(fc2W[j * 64 + k], c1W[k * 64 + c], s);
            W2c[j * 64 + c] = s;
        } else if (j == 32) {
            float s = 0.f;
            for (int k = 0; k < 64; ++k) s = fmaf(b2[k], c1W[k * 64 + c], s);
            b2c[c] = s;
        }
    }
}

// single-block scan: rowptr[i+1]=sum(cnt[0..i]); also disq[i] and cnt zero
__global__ __launch_bounds__(1024) void k_scan(int* __restrict__ cnt,
                                               int* __restrict__ rowptr,
                                               float* __restrict__ disq) {
    __shared__ int wsum[16];
    __shared__ int carry;
    int t = threadIdx.x, wave = t >> 6, lane = t & 63;
    if (t == 0) { carry = 0; rowptr[0] = 0; }
    __syncthreads();
    for (int base = 0; base < NN; base += 1024) {
        int i = base + t;
        int x = (i < NN) ? cnt[i] : 0;
        if (i < NN) {
            cnt[i] = 0;  // reset for k_fill cursor
            disq[i] = rsqrtf((float)x + 1.0f);  // +1 self-loop
        }
        for (int off = 1; off < 64; off <<= 1) {
            int y = __shfl_up(x, off, 64);
            if (lane >= off) x += y;
        }
        if (lane == 63) wsum[wave] = x;
        __syncthreads();
        if (wave == 0 && lane < 16) {
            int w = wsum[lane];
            for (int off = 1; off < 16; off <<= 1) {
                int y = __shfl_up(w, off, 16);
                if (lane >= off) w += y;
            }
            wsum[lane] = w;
        }
        __syncthreads();
        int incl = carry + ((wave > 0) ? wsum[wave - 1] : 0) + x;
        if (i < NN) rowptr[i + 1] = incl;
        __syncthreads();
        if (t == 1023) carry = incl;
        __syncthreads();
    }
}

// ---------------- dual-role: CSR bucket fill  ∥  fc stack (+conv1W folded) --
// fill blocks: latency-bound atomics/scatter. fc blocks: VALU-bound GEMV.
__global__ __launch_bounds__(256) void k_fill_fc(
    const int* __restrict__ src, const int* __restrict__ dst,
    const int* __restrict__ rowptr, int* __restrict__ cur,
    u16* __restrict__ esrc,
    const float* __restrict__ nf,
    const float* __restrict__ W1, const float* __restrict__ b1,
    const float* __restrict__ W2c, const float* __restrict__ b2c,
    const float* __restrict__ disq, u16* __restrict__ Hb) {
    if (blockIdx.x < FILL_BLOCKS) {
        int e = blockIdx.x * 256 + threadIdx.x;
        if (e < NE) {
            int d = dst[e];
            int pos = rowptr[d] + atomicAdd(&cur[d], 1);
            esrc[pos] = (u16)src[e];
        }
        return;
    }
    int lane = threadIdx.x & 63;
    int c = lane & 31, h = lane >> 5;
    int wid = ((blockIdx.x - FILL_BLOCKS) * 256 + threadIdx.x) >> 6;
    int nwaves = (FC_BLOCKS * 256) >> 6;
    float w1[64], w2[32];
    #pragma unroll
    for (int j = 0; j < 64; ++j) w1[j] = W1[(h * 64 + j) * 32 + c];
    #pragma unroll
    for (int j = 0; j < 32; ++j) w2[j] = W2c[j * 64 + lane];
    float b1c = b1[c], b2l = b2c[lane];
    for (int n = wid; n < NN; n += nwaves) {
        float x0 = nf[(size_t)n * 128 + lane];
        float x1 = nf[(size_t)n * 128 + 64 + lane];
        float s = 0.f;
        #pragma unroll
        for (int j = 0; j < 64; ++j) {
            float xa = rlf(x0, j), xb = rlf(x1, j);
            s = fmaf(h ? xb : xa, w1[j], s);
        }
        s += __shfl_xor(s, 32, 64);           // combine k-halves
        float hv = fmaxf(s + b1c, 0.f);       // lane l holds h1[l&31]
        float o = b2l;
        #pragma unroll
        for (int j = 0; j < 32; ++j) o = fmaf(rlf(hv, j), w2[j], o);
        Hb[(size_t)n * 64 + lane] = f2bf(disq[n] * o);
    }
}

// ---------------- conv GEMM: Hb[n] = bf16( disq[n] * (X[n] @ W) ) ----------
__global__ __launch_bounds__(256) void k_gemm64(
    const float* __restrict__ X, const float* __restrict__ W,
    const float* __restrict__ disq, u16* __restrict__ Hb) {
    int lane = threadIdx.x & 63;
    int wid = (blockIdx.x * 256 + threadIdx.x) >> 6;
    int nwaves = (gridDim.x * 256) >> 6;
    float wcol[64];
    #pragma unroll
    for (int k = 0; k < 64; ++k) wcol[k] = W[k * 64 + lane];
    for (int n = wid; n < NN; n += nwaves) {
        float xv = X[(size_t)n * 64 + lane];
        float acc = 0.f;
        #pragma unroll
        for (int k = 0; k < 64; ++k) acc = fmaf(rlf(xv, k), wcol[k], acc);
        Hb[(size_t)n * 64 + lane] = f2bf(disq[n] * acc);
    }
}

// ---------------- CSR conv, paired-row u32 gathers ----------------
// wave per node; lane owns channels (cl, cl+1); half-waves cover 2 rows/load
__global__ __launch_bounds__(256) void k_csr_conv(
    const u16* __restrict__ Hb, const int* __restrict__ rowptr,
    const u16* __restrict__ esrc, const float* __restrict__ disq,
    const float* __restrict__ b, const float* __restrict__ res,
    float* __restrict__ out, int do_lrelu) {
    int lane = threadIdx.x & 63;
    int half = lane >> 5;
    int cl = (lane & 31) * 2;
    int n = (blockIdx.x * 256 + threadIdx.x) >> 6;
    if (n >= NN) return;
    int beg = rowptr[n], end = rowptr[n + 1];
    float a0 = 0.f, a1 = 0.f;
    for (int base = beg; base < end; base += 64) {
        int cnt = min(64, end - base);
        int idx = (lane < cnt) ? (int)esrc[base + lane] : 0;
        int j = 0;
        for (; j + 8 <= cnt; j += 8) {
            int p0 = __builtin_amdgcn_readlane(idx, j + 0);
            int p1 = __builtin_amdgcn_readlane(idx, j + 1);
            int p2 = __builtin_amdgcn_readlane(idx, j + 2);
            int p3 = __builtin_amdgcn_readlane(idx, j + 3);
            int p4 = __builtin_amdgcn_readlane(idx, j + 4);
            int p5 = __builtin_amdgcn_readlane(idx, j + 5);
            int p6 = __builtin_amdgcn_readlane(idx, j + 6);
            int p7 = __builtin_amdgcn_readlane(idx, j + 7);
            int sA = half ? p1 : p0;
            int sB = half ? p3 : p2;
            int sC = half ? p5 : p4;
            int sD = half ? p7 : p6;
            u32 qA = *(const u32*)(Hb + ((size_t)sA * 64 + cl));
            u32 qB = *(const u32*)(Hb + ((size_t)sB * 64 + cl));
            u32 qC = *(const u32*)(Hb + ((size_t)sC * 64 + cl));
            u32 qD = *(const u32*)(Hb + ((size_t)sD * 64 + cl));
            a0 += (lo16(qA) + lo16(qB)) + (lo16(qC) + lo16(qD));
            a1 += (hi16(qA) + hi16(qB)) + (hi16(qC) + hi16(qD));
        }
        for (; j + 2 <= cnt; j += 2) {
            int p0 = __builtin_amdgcn_readlane(idx, j);
            int p1 = __builtin_amdgcn_readlane(idx, j + 1);
            int s = half ? p1 : p0;
            u32 q = *(const u32*)(Hb + ((size_t)s * 64 + cl));
            a0 += lo16(q);
            a1 += hi16(q);
        }
        if (j < cnt) {  // odd tail: half 0 only
            int s = __builtin_amdgcn_readlane(idx, j);
            if (!half) {
                u32 q = *(const u32*)(Hb + ((size_t)s * 64 + cl));
                a0 += lo16(q);
                a1 += hi16(q);
            }
        }
    }
    a0 += __shfl_xor(a0, 32, 64);  // combine even/odd row halves
    a1 += __shfl_xor(a1, 32, 64);
    u32 qs = *(const u32*)(Hb + ((size_t)n * 64 + cl));  // self-loop
    a0 += lo16(qs);
    a1 += hi16(qs);
    float dn = disq[n];
    float v0 = dn * a0 + b[cl];
    float v1 = dn * a1 + b[cl + 1];
    if (do_lrelu) {
        v0 = (v0 >= 0.f) ? v0 : 0.2f * v0;
        v1 = (v1 >= 0.f) ? v1 : 0.2f * v1;
    }
    if (res) {
        float2 r = *(const float2*)(res + ((size_t)n * 64 + cl));
        v0 += r.x;
        v1 += r.y;
    }
    if (!half) {
        float2 o;
        o.x = v0;
        o.y = v1;
        *(float2*)(out + ((size_t)n * 64 + cl)) = o;
    }
}

// ---------------- conv4 + residual + final 64->2 projection ----------------
__global__ __launch_bounds__(256) void k_csr_conv_final(
    const u16* __restrict__ Hb, const int* __restrict__ rowptr,
    const u16* __restrict__ esrc, const float* __restrict__ disq,
    const float* __restrict__ b, const float* __restrict__ res,
    const float* __restrict__ FW, const float* __restrict__ fb,
    float* __restrict__ out) {
    int lane = threadIdx.x & 63;
    int half = lane >> 5;
    int cl = (lane & 31) * 2;
    int n = (blockIdx.x * 256 + threadIdx.x) >> 6;
    if (n >= NN) return;
    int beg = rowptr[n], end = rowptr[n + 1];
    float a0 = 0.f, a1 = 0.f;
    for (int base = beg; base < end; base += 64) {
        int cnt = min(64, end - base);
        int idx = (lane < cnt) ? (int)esrc[base + lane] : 0;
        int j = 0;
        for (; j + 8 <= cnt; j += 8) {
            int p0 = __builtin_amdgcn_readlane(idx, j + 0);
            int p1 = __builtin_amdgcn_readlane(idx, j + 1);
            int p2 = __builtin_amdgcn_readlane(idx, j + 2);
            int p3 = __builtin_amdgcn_readlane(idx, j + 3);
            int p4 = __builtin_amdgcn_readlane(idx, j + 4);
            int p5 = __builtin_amdgcn_readlane(idx, j + 5);
            int p6 = __builtin_amdgcn_readlane(idx, j + 6);
            int p7 = __builtin_amdgcn_readlane(idx, j + 7);
            int sA = half ? p1 : p0;
            int sB = half ? p3 : p2;
            int sC = half ? p5 : p4;
            int sD = half ? p7 : p6;
            u32 qA = *(const u32*)(Hb + ((size_t)sA * 64 + cl));
            u32 qB = *(const u32*)(Hb + ((size_t)sB * 64 + cl));
            u32 qC = *(const u32*)(Hb + ((size_t)sC * 64 + cl));
            u32 qD = *(const u32*)(Hb + ((size_t)sD * 64 + cl));
            a0 += (lo16(qA) + lo16(qB)) + (lo16(qC) + lo16(qD));
            a1 += (hi16(qA) + hi16(qB)) + (hi16(qC) + hi16(qD));
        }
        for (; j + 2 <= cnt; j += 2) {
            int p0 = __builtin_amdgcn_readlane(idx, j);
            int p1 = __builtin_amdgcn_readlane(idx, j + 1);
            int s = half ? p1 : p0;
            u32 q = *(const u32*)(Hb + ((size_t)s * 64 + cl));
            a0 += lo16(q);
            a1 += hi16(q);
        }
        if (j < cnt) {
            int s = __builtin_amdgcn_readlane(idx, j);
            if (!half) {
                u32 q = *(const u32*)(Hb + ((size_t)s * 64 + cl));
                a0 += lo16(q);
                a1 += hi16(q);
            }
        }
    }
    a0 += __shfl_xor(a0, 32, 64);
    a1 += __shfl_xor(a1, 32, 64);
    u32 qs = *(const u32*)(Hb + ((size_t)n * 64 + cl));
    a0 += lo16(qs);
    a1 += hi16(qs);
    float dn = disq[n];
    float2 r = *(const float2*)(res + ((size_t)n * 64 + cl));
    float v0 = dn * a0 + b[cl] + r.x;       // out4, no lrelu
    float v1 = dn * a1 + b[cl + 1] + r.y;
    // projection: channels cl, cl+1 -> 2 outputs
    float p0 = v0 * FW[cl * 2 + 0] + v1 * FW[(cl + 1) * 2 + 0];
    float p1 = v0 * FW[cl * 2 + 1] + v1 * FW[(cl + 1) * 2 + 1];
    for (int off = 16; off; off >>= 1) {  // reduce within 32-lane half
        p0 += __shfl_xor(p0, off, 64);
        p1 += __shfl_xor(p1, off, 64);
    }
    if (lane == 0) {
        out[n * 2 + 0] = p0 + fb[0];
        out[n * 2 + 1] = p1 + fb[1];
    }
}

extern "C" void kernel_launch(void* const* d_in, const int* in_sizes, int n_in,
                              void* d_out, int out_size, void* d_ws, size_t ws_size,
                              hipStream_t stream) {
    const float* nf   = (const float*)d_in[0];
    const int*   ei   = (const int*)d_in[1];
    const float* fc1W = (const float*)d_in[2];
    const float* fc1b = (const float*)d_in[3];
    const float* fc2W = (const float*)d_in[4];
    const float* fc2b = (const float*)d_in[5];
    const float* cW[4] = {(const float*)d_in[6], (const float*)d_in[8],
                          (const float*)d_in[10], (const float*)d_in[12]};
    const float* cb[4] = {(const float*)d_in[7], (const float*)d_in[9],
                          (const float*)d_in[11], (const float*)d_in[13]};
    const float* fW = (const float*)d_in[14];
    const float* fb = (const float*)d_in[15];
    const int* src = ei;
    const int* dst = ei + NE;

    float* ws     = (float*)d_ws;
    float* disq   = ws;                          // 50048 f
    int*   cnt    = (int*)(ws + 50048);          // 50048 i (histogram, then cursor)
    int*   rowptr = cnt + 50048;                 // 50056 i
    u16*   esrc   = (u16*)(rowptr + 50056);      // 800000 u16 (400000 i)
    float* W2c    = (float*)(esrc + 800000);     // 2048 f
    float* b2c    = W2c + 2048;                  // 64 f
    float* B0     = b2c + 64;                    // NN*64 f
    float* B1     = B0 + (size_t)NN * 64;        // NN*64 f
    u16*   Hb     = (u16*)(B1 + (size_t)NN * 64);// NN*64 u16

    // ---- CSR build + weight fold + fc (overlapped) ----
    hipMemsetAsync(cnt, 0, 50048 * sizeof(int), stream);
    k_hist_foldw<<<HIST_BLOCKS + 9, 256, 0, stream>>>(dst, cnt, fc2W, fc2b, cW[0],
                                                      W2c, b2c);
    k_scan<<<1, 1024, 0, stream>>>(cnt, rowptr, disq);  // + disq, + cnt zero
    k_fill_fc<<<FILL_BLOCKS + FC_BLOCKS, 256, 0, stream>>>(
        src, dst, rowptr, cnt, esrc, nf, fc1W, fc1b, W2c, b2c, disq, Hb);

    const int cgrid = (NN * 64 + 255) / 256;  // one wave per node

    // conv1: out1 -> B1
    k_csr_conv<<<cgrid, 256, 0, stream>>>(Hb, rowptr, esrc, disq, cb[0], nullptr, B1, 1);
    // conv2: out2 = lrelu(conv)+out1 -> B0
    k_gemm64<<<512, 256, 0, stream>>>(B1, cW[1], disq, Hb);
    k_csr_conv<<<cgrid, 256, 0, stream>>>(Hb, rowptr, esrc, disq, cb[1], B1, B0, 1);
    // conv3: out3 -> B1
    k_gemm64<<<512, 256, 0, stream>>>(B0, cW[2], disq, Hb);
    k_csr_conv<<<cgrid, 256, 0, stream>>>(Hb, rowptr, esrc, disq, cb[2], nullptr, B1, 1);
    // conv4 + residual(out2=B0) + final projection -> d_out
    k_gemm64<<<512, 256, 0, stream>>>(B1, cW[3], disq, Hb);
    k_csr_conv_final<<<cgrid, 256, 0, stream>>>(Hb, rowptr, esrc, disq, cb[3], B0,
                                                fW, fb, (float*)d_out);
}